// Round 1
// baseline (274.522 us; speedup 1.0000x reference)
//
#include <hip/hip_runtime.h>

constexpr int H  = 256;
constexpr int H2 = 128;
constexpr int N  = 1024;
constexpr int T  = 12;
constexpr int B  = 4;
constexpr int M  = B * N; // 4096 total rows

// ---------------- k0: fold Wb into W2o (oW = relu(h)@ (W2o@Wb) + b2o@Wb) ----
__global__ void fold_wb_kernel(const float* __restrict__ W2o,
                               const float* __restrict__ b2o,
                               const float* __restrict__ Wb,
                               float* __restrict__ W2of,
                               float* __restrict__ b2of) {
    __shared__ float row[H2];
    const int i = blockIdx.x;            // 0..H-1: rows of W2o; i==H: b2o row
    const int j = threadIdx.x;           // 0..127
    const float* src = (i < H) ? (W2o + i * H2) : b2o;
    row[j] = src[j];
    __syncthreads();
    float acc = 0.f;
#pragma unroll 8
    for (int k = 0; k < H2; ++k) acc = fmaf(row[k], Wb[k * H2 + j], acc);
    if (i < H) W2of[i * H2 + j] = acc;
    else       b2of[j] = acc;
}

// ---------------- k1/k2: C = act(A @ W + bias), two branches via blockIdx.z --
// 64x64 tile, 256 threads, 4x4 micro-tile. LDS is K-major so the inner loop is
// two ds_read_b128 + 16 v_fma_f32 per k (ALU-bound; 2-way bank alias = free).
template<bool RELU, int BK>
__global__ __launch_bounds__(256) void gemm_bias_kernel(
    const float* __restrict__ A0, const float* __restrict__ A1,
    const float* __restrict__ W0, const float* __restrict__ W1,
    const float* __restrict__ bias0, const float* __restrict__ bias1,
    float* __restrict__ C0, float* __restrict__ C1,
    int Nout, int K)
{
    const int br = blockIdx.z;
    const float* A    = br ? A1 : A0;
    const float* W    = br ? W1 : W0;
    const float* bias = br ? bias1 : bias0;
    float*       C    = br ? C1 : C0;

    __shared__ float As[BK][68];   // [k][row]  (transposed A tile)
    __shared__ float Ws[BK][68];   // [k][col]

    const int tid = threadIdx.x;
    const int tx = tid & 15;
    const int ty = tid >> 4;
    const int row0 = blockIdx.y * 64;
    const int col0 = blockIdx.x * 64;

    float acc[4][4] = {};

    for (int kt = 0; kt < K; kt += BK) {
        // stage A tile (64 rows x BK k) -> transposed scatter
#pragma unroll
        for (int p = 0; p < (64 * BK / 4) / 256; ++p) {
            const int idx = tid + p * 256;
            const int r  = idx / (BK / 4);
            const int c4 = idx % (BK / 4);
            const float4 v = *(const float4*)(A + (size_t)(row0 + r) * K + kt + 4 * c4);
            As[4 * c4 + 0][r] = v.x;
            As[4 * c4 + 1][r] = v.y;
            As[4 * c4 + 2][r] = v.z;
            As[4 * c4 + 3][r] = v.w;
        }
        // stage W tile (BK k x 64 cols), already K-major
#pragma unroll
        for (int p = 0; p < (BK * 64 / 4) / 256; ++p) {
            const int idx = tid + p * 256;
            const int r  = idx / 16;
            const int c4 = idx % 16;
            *(float4*)&Ws[r][4 * c4] =
                *(const float4*)(W + (size_t)(kt + r) * Nout + col0 + 4 * c4);
        }
        __syncthreads();
#pragma unroll
        for (int k = 0; k < BK; ++k) {
            const float4 a4 = *(const float4*)&As[k][4 * ty];
            const float4 b4 = *(const float4*)&Ws[k][4 * tx];
            const float a[4] = {a4.x, a4.y, a4.z, a4.w};
            const float b[4] = {b4.x, b4.y, b4.z, b4.w};
#pragma unroll
            for (int i = 0; i < 4; ++i)
#pragma unroll
                for (int j = 0; j < 4; ++j)
                    acc[i][j] = fmaf(a[i], b[j], acc[i][j]);
        }
        __syncthreads();
    }

    const float4 bias4 = *(const float4*)(bias + col0 + 4 * tx);
    const float bj[4] = {bias4.x, bias4.y, bias4.z, bias4.w};
#pragma unroll
    for (int i = 0; i < 4; ++i) {
        float4 o;
        float v0 = acc[i][0] + bj[0];
        float v1 = acc[i][1] + bj[1];
        float v2 = acc[i][2] + bj[2];
        float v3 = acc[i][3] + bj[3];
        if (RELU) {
            v0 = fmaxf(v0, 0.f); v1 = fmaxf(v1, 0.f);
            v2 = fmaxf(v2, 0.f); v3 = fmaxf(v3, 0.f);
        }
        o.x = v0; o.y = v1; o.z = v2; o.w = v3;
        *(float4*)(C + (size_t)(row0 + 4 * ty + i) * Nout + col0 + 4 * tx) = o;
    }
}

// ---------------- k3: S = oW_b @ d_b^T + bb, fused horizon expansion --------
// Each block: 64x64 score tile (K=128), then writes T=12 output slices with
// coalesced float4 stores. relu(relu(x)) == relu(x).
template<int BK>
__global__ __launch_bounds__(256) void scores_expand_kernel(
    const float* __restrict__ oW, const float* __restrict__ dd,
    const float* __restrict__ bbp, const float* __restrict__ wh,
    const float* __restrict__ bh, float* __restrict__ out)
{
    __shared__ float As[BK][68];  // [k][i-row]
    __shared__ float Bs[BK][68];  // [k][j-row]
    const int tid = threadIdx.x;
    const int tx = tid & 15;
    const int ty = tid >> 4;
    const int b  = blockIdx.z;
    const int i0 = blockIdx.y * 64;
    const int j0 = blockIdx.x * 64;
    const float* Ab = oW + (size_t)b * N * H2;
    const float* Bb = dd + (size_t)b * N * H2;

    float acc[4][4] = {};

    for (int kt = 0; kt < H2; kt += BK) {
#pragma unroll
        for (int p = 0; p < (64 * BK / 4) / 256; ++p) {
            const int idx = tid + p * 256;
            const int r  = idx / (BK / 4);
            const int c4 = idx % (BK / 4);
            const float4 v = *(const float4*)(Ab + (size_t)(i0 + r) * H2 + kt + 4 * c4);
            As[4 * c4 + 0][r] = v.x;
            As[4 * c4 + 1][r] = v.y;
            As[4 * c4 + 2][r] = v.z;
            As[4 * c4 + 3][r] = v.w;
            const float4 w = *(const float4*)(Bb + (size_t)(j0 + r) * H2 + kt + 4 * c4);
            Bs[4 * c4 + 0][r] = w.x;
            Bs[4 * c4 + 1][r] = w.y;
            Bs[4 * c4 + 2][r] = w.z;
            Bs[4 * c4 + 3][r] = w.w;
        }
        __syncthreads();
#pragma unroll
        for (int k = 0; k < BK; ++k) {
            const float4 a4 = *(const float4*)&As[k][4 * ty];
            const float4 b4 = *(const float4*)&Bs[k][4 * tx];
            const float a[4] = {a4.x, a4.y, a4.z, a4.w};
            const float bfr[4] = {b4.x, b4.y, b4.z, b4.w};
#pragma unroll
            for (int i = 0; i < 4; ++i)
#pragma unroll
                for (int j = 0; j < 4; ++j)
                    acc[i][j] = fmaf(a[i], bfr[j], acc[i][j]);
        }
        __syncthreads();
    }

    const float bbv = bbp[0];
    float whr[T], bhr[T];
#pragma unroll
    for (int t = 0; t < T; ++t) { whr[t] = wh[t]; bhr[t] = bh[t]; }

    // add bilinear bias once
#pragma unroll
    for (int i = 0; i < 4; ++i)
#pragma unroll
        for (int j = 0; j < 4; ++j)
            acc[i][j] += bbv;

    // out[((b*T + t)*N + i)*N + j]
#pragma unroll
    for (int t = 0; t < T; ++t) {
        float* obase = out + ((size_t)(b * T + t) * N + i0 + 4 * ty) * N + j0 + 4 * tx;
#pragma unroll
        for (int i = 0; i < 4; ++i) {
            float4 o;
            o.x = fmaxf(fmaf(acc[i][0], whr[t], bhr[t]), 0.f);
            o.y = fmaxf(fmaf(acc[i][1], whr[t], bhr[t]), 0.f);
            o.z = fmaxf(fmaf(acc[i][2], whr[t], bhr[t]), 0.f);
            o.w = fmaxf(fmaf(acc[i][3], whr[t], bhr[t]), 0.f);
            *(float4*)(obase + (size_t)i * N) = o;
        }
    }
}

extern "C" void kernel_launch(void* const* d_in, const int* in_sizes, int n_in,
                              void* d_out, int out_size, void* d_ws, size_t ws_size,
                              hipStream_t stream) {
    const float* x   = (const float*)d_in[0];
    const float* W1o = (const float*)d_in[1];
    const float* b1o = (const float*)d_in[2];
    const float* W2o = (const float*)d_in[3];
    const float* b2o = (const float*)d_in[4];
    const float* W1d = (const float*)d_in[5];
    const float* b1d = (const float*)d_in[6];
    const float* W2d = (const float*)d_in[7];
    const float* b2d = (const float*)d_in[8];
    const float* Wb  = (const float*)d_in[9];
    const float* bb  = (const float*)d_in[10];
    const float* wh  = (const float*)d_in[11];
    const float* bh  = (const float*)d_in[12];
    float* out = (float*)d_out;

    // workspace layout (floats): 12.7 MB total
    float* ws   = (float*)d_ws;
    float* W2of = ws;                 // H*H2   = 32768
    float* b2of = W2of + H * H2;      // H2     = 128
    float* oW   = b2of + H2;          // M*H2   = 524288
    float* dd   = oW + (size_t)M * H2;
    float* h_o  = dd + (size_t)M * H2;   // M*H = 1048576
    float* h_d  = h_o + (size_t)M * H;

    // k0: fold bilinear weight into origin branch's 2nd layer
    fold_wb_kernel<<<H + 1, H2, 0, stream>>>(W2o, b2o, Wb, W2of, b2of);

    // k1: h = relu(x @ W1 + b1) for both branches (z = branch)
    gemm_bias_kernel<true, 32><<<dim3(H / 64, M / 64, 2), 256, 0, stream>>>(
        x, x, W1o, W1d, b1o, b1d, h_o, h_d, H, H);

    // k2: oW = h_o @ W2o' + b2o' ; d = h_d @ W2d + b2d
    gemm_bias_kernel<false, 32><<<dim3(H2 / 64, M / 64, 2), 256, 0, stream>>>(
        h_o, h_d, W2of, W2d, b2of, b2d, oW, dd, H2, H);

    // k3: scores + horizon expansion, writes the full (B,T,N,N) output
    scores_expand_kernel<64><<<dim3(N / 64, N / 64, B), 256, 0, stream>>>(
        oW, dd, bb, wh, bh, out);
}